// Round 15
// baseline (463.008 us; speedup 1.0000x reference)
//
#include <hip/hip_runtime.h>
#include <math.h>
#include <float.h>

#define EPSV 1e-8f
constexpr int D = 64;

typedef __attribute__((ext_vector_type(8)))  short short8;
typedef __attribute__((ext_vector_type(16))) float f32x16;

static __device__ __forceinline__ unsigned short f2bf(float f) {
    unsigned u = __float_as_uint(f);
    unsigned r = u + 0x7FFFu + ((u >> 16) & 1u);   // round-to-nearest-even
    return (unsigned short)(r >> 16);
}
static __device__ __forceinline__ float bf2f(unsigned short b) {
    return __uint_as_float(((unsigned)b) << 16);
}
static __device__ __forceinline__ unsigned umin2(unsigned a, unsigned b) { return a < b ? a : b; }
static __device__ __forceinline__ unsigned umax2(unsigned a, unsigned b) { return a > b ? a : b; }

// fragment-ready layout: entity panel p=e>>5, k-slot q=k>>3:
//   u16 index = p*2048 + q*256 + (e&31)*8 + (k&7)
static __device__ __forceinline__ size_t fragidx(int e, int k) {
    return (size_t)(e >> 5) * 2048 + (size_t)(k >> 3) * 256 + (e & 31) * 8 + (k & 7);
}

// ---------------------------------------------------------------------------
// prep: normalize codebook. cb fp32 (for gather) + double-normalized hi/lo
// bf16 fragments.
// ---------------------------------------------------------------------------
__global__ __launch_bounds__(256) void k_prep_cb(const float* __restrict__ cbin,
                                                 float* __restrict__ cb,
                                                 unsigned short* __restrict__ ch,
                                                 unsigned short* __restrict__ cl) {
    const int t = threadIdx.x;
    const int wv = t >> 6, lane = t & 63;
    const int code = blockIdx.x * 4 + wv;
    float v = cbin[(size_t)code * D + lane];
    float ss = v * v;
    #pragma unroll
    for (int off = 32; off; off >>= 1) ss += __shfl_xor(ss, off, 64);
    const float c1 = v / (sqrtf(ss) + EPSV);
    cb[(size_t)code * D + lane] = c1;
    float ss2 = c1 * c1;
    #pragma unroll
    for (int off = 32; off; off >>= 1) ss2 += __shfl_xor(ss2, off, 64);
    const float c2 = c1 / (sqrtf(ss2) + EPSV);
    const unsigned short h = f2bf(c2);
    const size_t fi = fragidx(code, lane);
    ch[fi] = h;
    cl[fi] = f2bf(c2 - bf2f(h));
}

// ---------------------------------------------------------------------------
// prep: normalize x -> xn (fp32, straight to d_out region 2) + hi/lo fragments
// also zeroes fixcnt (stream-ordered before k_reduce2)
// ---------------------------------------------------------------------------
__global__ __launch_bounds__(256) void k_prep_x(const float* __restrict__ xin,
                                                float* __restrict__ xn,
                                                unsigned short* __restrict__ xh,
                                                unsigned short* __restrict__ xl,
                                                int* __restrict__ fixcnt) {
    const int t = threadIdx.x;
    if (blockIdx.x == 0 && t == 0) *fixcnt = 0;
    const int wv = t >> 6, lane = t & 63;
    const int row = blockIdx.x * 4 + wv;
    float v = xin[(size_t)row * D + lane];
    float ss = v * v;
    #pragma unroll
    for (int off = 32; off; off >>= 1) ss += __shfl_xor(ss, off, 64);
    const float xv = v / (sqrtf(ss) + EPSV);
    xn[(size_t)row * D + lane] = xv;
    const unsigned short h = f2bf(xv);
    const size_t fi = fragidx(row, lane);
    xh[fi] = h;
    xl[fi] = f2bf(xv - bf2f(h));
}

// ---------------------------------------------------------------------------
// main: 128 rows x 2048 codes per block (32 tiles of 64 codes), 4 waves.
// PHASE 1 (per wave, private): read own 32 rows x 2048 codes with 8KB
//   contiguous streaks per row (32 coalesced 256B loads, 2-row lookahead),
//   ballot -> bit words -> lane0 ds_write_b64 into LDS lbits[128][68].
// PHASE 2 (per wave, private): R13's compute loop; bit words from LDS.
// NO barriers (LDS strictly wave-private); waves drift so phase1 memory
// overlaps other waves' phase2 MFMA. Mask read ONCE at streaming granule.
// ---------------------------------------------------------------------------
__global__ __launch_bounds__(256, 3) void k_mfma(const unsigned short* __restrict__ xh,
                                                 const unsigned short* __restrict__ xl,
                                                 const unsigned short* __restrict__ ch,
                                                 const unsigned short* __restrict__ cl,
                                                 const int* __restrict__ mask,
                                                 const int* __restrict__ training,
                                                 unsigned* __restrict__ pk1,
                                                 unsigned* __restrict__ pk2,
                                                 int B, int K) {
    __shared__ unsigned lbits[128][68];          // ~34.8 KB, row-padded (68)
    const int t = threadIdx.x;
    const int wv = t >> 6, lane = t & 63;
    const int lh = lane >> 5, lm = lane & 31;
    const int ks = (int)(blockIdx.x & 7);
    const int rb = (int)(blockIdx.x >> 3);
    const int tr = training[0];

    const short8* xh8 = (const short8*)xh;
    const short8* xl8 = (const short8*)xl;
    const short8* ch8 = (const short8*)ch;
    const short8* cl8 = (const short8*)cl;

    const int rp = rb * 4 + wv;                  // this wave's 32-row panel
    const int row = rp * 32 + lm;                // this lane's x-row
    const int lh4 = lh * 4;

    // B fragments (x rows), held for the whole block
    short8 bh[4], bl[4];
    #pragma unroll
    for (int s = 0; s < 4; ++s) {
        const size_t bi = (size_t)rp * 256 + (s * 2 + lh) * 32 + lm;
        bh[s] = xh8[bi];
        bl[s] = xl8[bi];
    }

    // ---------------- PHASE 1: transpose mask slice into LDS bits ----------
    const int* mrow = mask + (size_t)(rp * 32) * K + ks * 2048;

#define LOADROW(dst_, r_) do {                                                 \
    _Pragma("unroll")                                                          \
    for (int i = 0; i < 32; ++i)                                               \
        dst_[i] = mrow[(size_t)(r_) * K + i * 64 + lane];                      \
} while (0)

#define BALROW(src_, r_) do {                                                  \
    _Pragma("unroll")                                                          \
    for (int i = 0; i < 32; ++i) {                                             \
        const unsigned long long b = __ballot(src_[i] != 0 || tr == 0);        \
        if (lane == 0)                                                         \
            *(unsigned long long*)&lbits[wv * 32 + (r_)][i * 2] = b;           \
    }                                                                          \
} while (0)

    {
        int va[32], vb[32];
        LOADROW(va, 0);
        #pragma unroll 1
        for (int r = 0; r < 32; r += 2) {
            LOADROW(vb, r + 1);                  // in flight over ballots of va
            BALROW(va, r);
            if (r + 2 < 32) LOADROW(va, r + 2);  // in flight over ballots of vb
            BALROW(vb, r + 1);
        }
    }
#undef BALROW
#undef LOADROW

    // ---------------- PHASE 2: MFMA + lane-local argmin --------------------
    unsigned k1 = 0xFFFFFFFFu, k2 = 0xFFFFFFFFu;

    #pragma unroll 1
    for (int tt = 0; tt < 32; ++tt) {
        const unsigned cw0 = lbits[wv * 32 + lm][tt * 2];
        const unsigned cw1 = lbits[wv * 32 + lm][tt * 2 + 1];
        const int ct = ks * 32 + tt;             // global 64-code tile id
        #pragma unroll
        for (int p = 0; p < 2; ++p) {
            const int cp = ct * 2 + p;           // code panel of 32
            short8 ah[4], al[4];
            #pragma unroll
            for (int s = 0; s < 4; ++s) {
                const size_t ai = (size_t)cp * 256 + (s * 2 + lh) * 32 + lm;
                ah[s] = ch8[ai];
                al[s] = cl8[ai];
            }
            f32x16 acc;
            #pragma unroll
            for (int i = 0; i < 16; ++i) acc[i] = 0.f;
            #pragma unroll
            for (int s = 0; s < 4; ++s) {
                acc = __builtin_amdgcn_mfma_f32_32x32x16_bf16(ah[s], bh[s], acc, 0, 0, 0);
                acc = __builtin_amdgcn_mfma_f32_32x32x16_bf16(ah[s], bl[s], acc, 0, 0, 0);
                acc = __builtin_amdgcn_mfma_f32_32x32x16_bf16(al[s], bh[s], acc, 0, 0, 0);
            }
            const unsigned wp = p ? cw1 : cw0;
            const unsigned nm2 = tr ? ((~wp) >> lh4) : 0u;   // bit=1 -> dropped
            const unsigned kbase = (unsigned)(ct * 64 + p * 32 + lh4);
            #pragma unroll
            for (int r = 0; r < 16; ++r) {
                const int base = (r & 3) + 8 * (r >> 2);              // static
                const float qf = fmaf(acc[r], -65536.0f, 131072.0f);
                int qi = (int)qf;
                qi = qi < 0 ? 0 : (qi > 262143 ? 262143 : qi);
                unsigned key = ((unsigned)qi << 14) | kbase | (unsigned)base;
                key |= (unsigned)((int)(nm2 << (31 - base)) >> 31);   // dropped
                k2 = umin2(k2, umax2(k1, key));
                k1 = umin2(k1, key);
            }
        }
    }

    // merge the two half-lanes holding the same x-row
    const unsigned o1 = (unsigned)__shfl_xor((int)k1, 32, 64);
    const unsigned o2 = (unsigned)__shfl_xor((int)k2, 32, 64);
    const unsigned mx = umax2(k1, o1);
    k1 = umin2(k1, o1);
    k2 = umin2(umin2(k2, o2), mx);

    if (lh == 0) {                               // coalesced 32-dword writes
        pk1[(size_t)ks * B + row] = k1;
        pk2[(size_t)ks * B + row] = k2;
    }
}

// ---------------------------------------------------------------------------
// combine the 8 ksplit partials per row; flag rows with top-2 gap < 10 quanta
// ---------------------------------------------------------------------------
__global__ __launch_bounds__(256) void k_reduce2(const unsigned* __restrict__ pk1,
                                                 const unsigned* __restrict__ pk2,
                                                 int* __restrict__ bestidx,
                                                 int* __restrict__ fixlist,
                                                 int* __restrict__ fixcnt,
                                                 int B) {
    const int row = blockIdx.x * 256 + threadIdx.x;
    unsigned k1 = 0xFFFFFFFFu, k2 = 0xFFFFFFFFu;
    #pragma unroll
    for (int c = 0; c < 8; ++c) {
        const unsigned a1 = pk1[(size_t)c * B + row];
        const unsigned a2 = pk2[(size_t)c * B + row];
        k2 = umin2(umin2(k2, a2), umax2(k1, a1));
        k1 = umin2(k1, a1);
    }
    bestidx[row] = (int)(k1 & 16383u);
    if ((k2 >> 14) - (k1 >> 14) < 10u) {
        const int p = atomicAdd(fixcnt, 1);
        fixlist[p] = row;
    }
}

// ---------------------------------------------------------------------------
// gather + write all outputs
// ---------------------------------------------------------------------------
__global__ __launch_bounds__(256) void k_out(const float* __restrict__ xn,
                                             const float* __restrict__ cb,
                                             const int* __restrict__ bestidx,
                                             float* __restrict__ out, int B) {
    const int t = threadIdx.x;
    const int wv = t >> 6, lane = t & 63;
    const int row = blockIdx.x * 4 + wv;
    const int bi = bestidx[row];
    const float zv  = cb[(size_t)bi * D + lane];
    const float xnv = xn[(size_t)row * D + lane];
    out[(size_t)row * D + lane] = xnv + (zv - xnv);                 // z_q
    out[(size_t)B * D + (size_t)row * D + lane] = zv;               // z
    if (lane == 0) out[(size_t)3 * B * D + row] = (float)bi;        // index
}

// ---------------------------------------------------------------------------
// exact fp32 rescan for flagged (near-tie) rows; overwrites their outputs
// ---------------------------------------------------------------------------
__global__ __launch_bounds__(256) void k_fix(const float* __restrict__ xn,
                                             const float* __restrict__ cb,
                                             const int* __restrict__ mask,
                                             const int* __restrict__ training,
                                             const int* __restrict__ fixlist,
                                             const int* __restrict__ fixcnt,
                                             float* __restrict__ out, int B, int K) {
    const int nf = *fixcnt;
    const int tr = training[0];
    __shared__ float sv[256];
    __shared__ int   si[256];
    const int t = threadIdx.x;
    for (int i = blockIdx.x; i < nf; i += gridDim.x) {
        const int row = fixlist[i];
        const float* xr = xn + (size_t)row * D;
        float b1 = FLT_MAX; int i1 = 0;
        for (int k = t; k < K; k += 256) {
            const float* cr = cb + (size_t)k * D;
            float s = 0.f;
            #pragma unroll
            for (int d = 0; d < D; ++d) s = fmaf(xr[d], cr[d], s);
            const int m = mask[(size_t)row * K + k];
            const float dist = (tr && m == 0) ? 1000000000.0f : -s;
            if (dist < b1) { b1 = dist; i1 = k; }
        }
        sv[t] = b1; si[t] = i1;
        __syncthreads();
        for (int s = 128; s; s >>= 1) {
            if (t < s) {
                const float ov = sv[t + s]; const int oi = si[t + s];
                if (ov < sv[t] || (ov == sv[t] && oi < si[t])) { sv[t] = ov; si[t] = oi; }
            }
            __syncthreads();
        }
        const int bi = si[0];
        if (t < 64) {
            const float zv  = cb[(size_t)bi * D + t];
            const float xnv = xr[t];
            out[(size_t)row * D + t] = xnv + (zv - xnv);
            out[(size_t)B * D + (size_t)row * D + t] = zv;
        }
        if (t == 0) out[(size_t)3 * B * D + row] = (float)bi;
        __syncthreads();
    }
}

extern "C" void kernel_launch(void* const* d_in, const int* in_sizes, int n_in,
                              void* d_out, int out_size, void* d_ws, size_t ws_size,
                              hipStream_t stream) {
    const float* x    = (const float*)d_in[0];
    const float* cbin = (const float*)d_in[1];
    const int* mask   = (const int*)d_in[2];
    const int* train  = (const int*)d_in[3];
    const int B = in_sizes[0] / D;   // 16384
    const int K = in_sizes[1] / D;   // 16384
    float* out = (float*)d_out;
    float* out_xn = out + (size_t)2 * B * D;

    char* w = (char*)d_ws;
    float* cbw          = (float*)w;                               // 4 MB
    unsigned short* xhw = (unsigned short*)(w + (size_t)K * D * 4);
    unsigned short* xlw = xhw + (size_t)B * D;
    unsigned short* chw = xlw + (size_t)B * D;
    unsigned short* clw = chw + (size_t)K * D;
    unsigned* pk1       = (unsigned*)(clw + (size_t)K * D);        // B*8 u32
    unsigned* pk2       = pk1 + (size_t)B * 8;                     // B*8 u32
    int* bestidx        = (int*)(pk2 + (size_t)B * 8);
    int* fixlist        = bestidx + B;
    int* fixcnt         = fixlist + B;

    k_prep_cb<<<K / 4, 256, 0, stream>>>(cbin, cbw, chw, clw);
    k_prep_x <<<B / 4, 256, 0, stream>>>(x, out_xn, xhw, xlw, fixcnt);
    k_mfma   <<<(B / 128) * 8, 256, 0, stream>>>(xhw, xlw, chw, clw, mask, train,
                                                 pk1, pk2, B, K);
    k_reduce2<<<B / 256, 256, 0, stream>>>(pk1, pk2, bestidx, fixlist, fixcnt, B);
    k_out    <<<B / 4, 256, 0, stream>>>(out_xn, cbw, bestidx, out, B);
    k_fix    <<<256, 256, 0, stream>>>(out_xn, cbw, mask, train, fixlist, fixcnt,
                                       out, B, K);
}

// Round 16
// 259.245 us; speedup vs baseline: 1.7860x; 1.7860x over previous
//
#include <hip/hip_runtime.h>
#include <math.h>
#include <float.h>

#define EPSV 1e-8f
constexpr int D = 64;

typedef __attribute__((ext_vector_type(8)))  short short8;
typedef __attribute__((ext_vector_type(16))) float f32x16;

static __device__ __forceinline__ unsigned short f2bf(float f) {
    unsigned u = __float_as_uint(f);
    unsigned r = u + 0x7FFFu + ((u >> 16) & 1u);   // round-to-nearest-even
    return (unsigned short)(r >> 16);
}
static __device__ __forceinline__ float bf2f(unsigned short b) {
    return __uint_as_float(((unsigned)b) << 16);
}
static __device__ __forceinline__ unsigned umin2(unsigned a, unsigned b) { return a < b ? a : b; }
static __device__ __forceinline__ unsigned umax2(unsigned a, unsigned b) { return a > b ? a : b; }

// fragment-ready layout: entity panel p=e>>5, k-slot q=k>>3:
//   u16 index = p*2048 + q*256 + (e&31)*8 + (k&7)
static __device__ __forceinline__ size_t fragidx(int e, int k) {
    return (size_t)(e >> 5) * 2048 + (size_t)(k >> 3) * 256 + (e & 31) * 8 + (k & 7);
}

// ---------------------------------------------------------------------------
// prep: normalize codebook. cb fp32 (for gather) + double-normalized hi/lo
// bf16 fragments.
// ---------------------------------------------------------------------------
__global__ __launch_bounds__(256) void k_prep_cb(const float* __restrict__ cbin,
                                                 float* __restrict__ cb,
                                                 unsigned short* __restrict__ ch,
                                                 unsigned short* __restrict__ cl) {
    const int t = threadIdx.x;
    const int wv = t >> 6, lane = t & 63;
    const int code = blockIdx.x * 4 + wv;
    float v = cbin[(size_t)code * D + lane];
    float ss = v * v;
    #pragma unroll
    for (int off = 32; off; off >>= 1) ss += __shfl_xor(ss, off, 64);
    const float c1 = v / (sqrtf(ss) + EPSV);
    cb[(size_t)code * D + lane] = c1;
    float ss2 = c1 * c1;
    #pragma unroll
    for (int off = 32; off; off >>= 1) ss2 += __shfl_xor(ss2, off, 64);
    const float c2 = c1 / (sqrtf(ss2) + EPSV);
    const unsigned short h = f2bf(c2);
    const size_t fi = fragidx(code, lane);
    ch[fi] = h;
    cl[fi] = f2bf(c2 - bf2f(h));
}

// ---------------------------------------------------------------------------
// prep: normalize x -> xn (fp32, straight to d_out region 2) + hi/lo fragments
// also zeroes fixcnt (stream-ordered before k_reduce2)
// ---------------------------------------------------------------------------
__global__ __launch_bounds__(256) void k_prep_x(const float* __restrict__ xin,
                                                float* __restrict__ xn,
                                                unsigned short* __restrict__ xh,
                                                unsigned short* __restrict__ xl,
                                                int* __restrict__ fixcnt) {
    const int t = threadIdx.x;
    if (blockIdx.x == 0 && t == 0) *fixcnt = 0;
    const int wv = t >> 6, lane = t & 63;
    const int row = blockIdx.x * 4 + wv;
    float v = xin[(size_t)row * D + lane];
    float ss = v * v;
    #pragma unroll
    for (int off = 32; off; off >>= 1) ss += __shfl_xor(ss, off, 64);
    const float xv = v / (sqrtf(ss) + EPSV);
    xn[(size_t)row * D + lane] = xv;
    const unsigned short h = f2bf(xv);
    const size_t fi = fragidx(row, lane);
    xh[fi] = h;
    xl[fi] = f2bf(xv - bf2f(h));
}

// ---------------------------------------------------------------------------
// main: 128 rows x 2048 codes per block (32 tiles of 64 codes), 4 waves.
// MASK-FREE: pure GEMM + per-lane top-2 of key=(q<<14)|code (u32-min).
// Swapped MFMA (A=codes, B=x-rows): acc col = x-row -> lane-local argmin.
// The mask is applied later, on candidates only (k_reduce2), with a sound
// flag+exact-rescan net for everything the candidate set could miss.
// ---------------------------------------------------------------------------
__global__ __launch_bounds__(256, 4) void k_mfma(const unsigned short* __restrict__ xh,
                                                 const unsigned short* __restrict__ xl,
                                                 const unsigned short* __restrict__ ch,
                                                 const unsigned short* __restrict__ cl,
                                                 unsigned* __restrict__ pk1,
                                                 unsigned* __restrict__ pk2,
                                                 int B, int K) {
    const int t = threadIdx.x;
    const int wv = t >> 6, lane = t & 63;
    const int lh = lane >> 5, lm = lane & 31;
    const int ks = (int)(blockIdx.x & 7);        // k-split (XCD-affine slice)
    const int rb = (int)(blockIdx.x >> 3);
    const int lh4 = lh * 4;

    const short8* xh8 = (const short8*)xh;
    const short8* xl8 = (const short8*)xl;
    const short8* ch8 = (const short8*)ch;
    const short8* cl8 = (const short8*)cl;

    const int rp = rb * 4 + wv;                  // this wave's 32-row panel
    const int row = rp * 32 + lm;                // this lane's x-row

    // B fragments (x rows), held for the whole block
    short8 bh[4], bl[4];
    #pragma unroll
    for (int s = 0; s < 4; ++s) {
        const size_t bi = (size_t)rp * 256 + (s * 2 + lh) * 32 + lm;
        bh[s] = xh8[bi];
        bl[s] = xl8[bi];
    }

    unsigned k1 = 0xFFFFFFFFu, k2 = 0xFFFFFFFFu;

    #pragma unroll 1
    for (int tt = 0; tt < 32; ++tt) {
        const int ct = ks * 32 + tt;             // global 64-code tile id
        #pragma unroll
        for (int p = 0; p < 2; ++p) {
            const int cp = ct * 2 + p;           // code panel of 32
            short8 ah[4], al[4];
            #pragma unroll
            for (int s = 0; s < 4; ++s) {
                const size_t ai = (size_t)cp * 256 + (s * 2 + lh) * 32 + lm;
                ah[s] = ch8[ai];
                al[s] = cl8[ai];
            }
            f32x16 acc;
            #pragma unroll
            for (int i = 0; i < 16; ++i) acc[i] = 0.f;
            #pragma unroll
            for (int s = 0; s < 4; ++s) {
                acc = __builtin_amdgcn_mfma_f32_32x32x16_bf16(ah[s], bh[s], acc, 0, 0, 0);
                acc = __builtin_amdgcn_mfma_f32_32x32x16_bf16(ah[s], bl[s], acc, 0, 0, 0);
                acc = __builtin_amdgcn_mfma_f32_32x32x16_bf16(al[s], bh[s], acc, 0, 0, 0);
            }
            const unsigned kbase = (unsigned)(ct * 64 + p * 32 + lh4);
            #pragma unroll
            for (int r = 0; r < 16; ++r) {
                const int base = (r & 3) + 8 * (r >> 2);              // static
                const float qf = fmaf(acc[r], -65536.0f, 131072.0f);  // dist*2^16+2^17
                int qi = (int)qf;
                qi = qi < 0 ? 0 : (qi > 262143 ? 262143 : qi);
                const unsigned key = ((unsigned)qi << 14) | kbase | (unsigned)base;
                k2 = umin2(k2, umax2(k1, key));
                k1 = umin2(k1, key);
            }
        }
    }

    // merge the two half-lanes holding the same x-row
    const unsigned o1 = (unsigned)__shfl_xor((int)k1, 32, 64);
    const unsigned o2 = (unsigned)__shfl_xor((int)k2, 32, 64);
    const unsigned mx = umax2(k1, o1);
    k1 = umin2(k1, o1);
    k2 = umin2(umin2(k2, o2), mx);

    if (lh == 0) {                               // coalesced 32-dword writes
        pk1[(size_t)ks * B + row] = k1;
        pk2[(size_t)ks * B + row] = k2;
    }
}

// ---------------------------------------------------------------------------
// combine: per row, 8 splits x (top-1, top-2) candidates. Apply the mask ONLY
// at candidate positions. Winner = min unmasked key. Flag for exact rescan:
//  (a) no unmasked candidate;
//  (b) near-tie: second_unmasked < winner + 10 quanta (quantization safety);
//  (c) hidden risk: any split with BOTH candidates masked whose k2 <
//      winner + 10 quanta (unseen codes of that split are all > its k2).
// ---------------------------------------------------------------------------
__global__ __launch_bounds__(256) void k_reduce2(const unsigned* __restrict__ pk1,
                                                 const unsigned* __restrict__ pk2,
                                                 const int* __restrict__ mask,
                                                 const int* __restrict__ training,
                                                 int* __restrict__ bestidx,
                                                 int* __restrict__ fixlist,
                                                 int* __restrict__ fixcnt,
                                                 int B, int K) {
    const int row = blockIdx.x * 256 + threadIdx.x;
    const int tr = training[0];
    unsigned a1[8], a2[8];
    #pragma unroll
    for (int c = 0; c < 8; ++c) {
        a1[c] = pk1[(size_t)c * B + row];
        a2[c] = pk2[(size_t)c * B + row];
    }
    int m1[8], m2[8];
    #pragma unroll
    for (int c = 0; c < 8; ++c) {
        m1[c] = (tr == 0) ? 1 : mask[(size_t)row * K + (a1[c] & 16383u)];
        m2[c] = (tr == 0) ? 1 : mask[(size_t)row * K + (a2[c] & 16383u)];
    }
    unsigned best = 0xFFFFFFFFu, second = 0xFFFFFFFFu;
    #pragma unroll
    for (int c = 0; c < 8; ++c) {
        if (m1[c] != 0) {
            const unsigned k = a1[c];
            if (k < best) { second = best; best = k; } else if (k < second) second = k;
        }
        if (m2[c] != 0) {
            const unsigned k = a2[c];
            if (k < best) { second = best; best = k; } else if (k < second) second = k;
        }
    }
    const unsigned long long lim = (unsigned long long)best + (10ull << 14);
    bool flag = (best == 0xFFFFFFFFu);
    if ((unsigned long long)second < lim) flag = true;               // near-tie
    #pragma unroll
    for (int c = 0; c < 8; ++c)
        if (m1[c] == 0 && m2[c] == 0 && (unsigned long long)a2[c] < lim)
            flag = true;                                             // hidden risk
    bestidx[row] = (int)(best & 16383u);
    if (flag) {
        const int p = atomicAdd(fixcnt, 1);
        fixlist[p] = row;
    }
}

// ---------------------------------------------------------------------------
// gather + write all outputs
// ---------------------------------------------------------------------------
__global__ __launch_bounds__(256) void k_out(const float* __restrict__ xn,
                                             const float* __restrict__ cb,
                                             const int* __restrict__ bestidx,
                                             float* __restrict__ out, int B) {
    const int t = threadIdx.x;
    const int wv = t >> 6, lane = t & 63;
    const int row = blockIdx.x * 4 + wv;
    const int bi = bestidx[row];
    const float zv  = cb[(size_t)bi * D + lane];
    const float xnv = xn[(size_t)row * D + lane];
    out[(size_t)row * D + lane] = xnv + (zv - xnv);                 // z_q
    out[(size_t)B * D + (size_t)row * D + lane] = zv;               // z
    if (lane == 0) out[(size_t)3 * B * D + row] = (float)bi;        // index
}

// ---------------------------------------------------------------------------
// exact fp32 rescan for flagged rows; overwrites their outputs
// ---------------------------------------------------------------------------
__global__ __launch_bounds__(256) void k_fix(const float* __restrict__ xn,
                                             const float* __restrict__ cb,
                                             const int* __restrict__ mask,
                                             const int* __restrict__ training,
                                             const int* __restrict__ fixlist,
                                             const int* __restrict__ fixcnt,
                                             float* __restrict__ out, int B, int K) {
    const int nf = *fixcnt;
    const int tr = training[0];
    __shared__ float sv[256];
    __shared__ int   si[256];
    const int t = threadIdx.x;
    for (int i = blockIdx.x; i < nf; i += gridDim.x) {
        const int row = fixlist[i];
        const float* xr = xn + (size_t)row * D;
        float b1 = FLT_MAX; int i1 = 0;
        for (int k = t; k < K; k += 256) {
            const float* cr = cb + (size_t)k * D;
            float s = 0.f;
            #pragma unroll
            for (int d = 0; d < D; ++d) s = fmaf(xr[d], cr[d], s);
            const int m = mask[(size_t)row * K + k];
            const float dist = (tr && m == 0) ? 1000000000.0f : -s;
            if (dist < b1) { b1 = dist; i1 = k; }
        }
        sv[t] = b1; si[t] = i1;
        __syncthreads();
        for (int s = 128; s; s >>= 1) {
            if (t < s) {
                const float ov = sv[t + s]; const int oi = si[t + s];
                if (ov < sv[t] || (ov == sv[t] && oi < si[t])) { sv[t] = ov; si[t] = oi; }
            }
            __syncthreads();
        }
        const int bi = si[0];
        if (t < 64) {
            const float zv  = cb[(size_t)bi * D + t];
            const float xnv = xr[t];
            out[(size_t)row * D + t] = xnv + (zv - xnv);
            out[(size_t)B * D + (size_t)row * D + t] = zv;
        }
        if (t == 0) out[(size_t)3 * B * D + row] = (float)bi;
        __syncthreads();
    }
}

extern "C" void kernel_launch(void* const* d_in, const int* in_sizes, int n_in,
                              void* d_out, int out_size, void* d_ws, size_t ws_size,
                              hipStream_t stream) {
    const float* x    = (const float*)d_in[0];
    const float* cbin = (const float*)d_in[1];
    const int* mask   = (const int*)d_in[2];
    const int* train  = (const int*)d_in[3];
    const int B = in_sizes[0] / D;   // 16384
    const int K = in_sizes[1] / D;   // 16384
    float* out = (float*)d_out;
    float* out_xn = out + (size_t)2 * B * D;

    char* w = (char*)d_ws;
    float* cbw          = (float*)w;                               // 4 MB
    unsigned short* xhw = (unsigned short*)(w + (size_t)K * D * 4);
    unsigned short* xlw = xhw + (size_t)B * D;
    unsigned short* chw = xlw + (size_t)B * D;
    unsigned short* clw = chw + (size_t)K * D;
    unsigned* pk1       = (unsigned*)(clw + (size_t)K * D);        // B*8 u32
    unsigned* pk2       = pk1 + (size_t)B * 8;                     // B*8 u32
    int* bestidx        = (int*)(pk2 + (size_t)B * 8);
    int* fixlist        = bestidx + B;
    int* fixcnt         = fixlist + B;

    k_prep_cb<<<K / 4, 256, 0, stream>>>(cbin, cbw, chw, clw);
    k_prep_x <<<B / 4, 256, 0, stream>>>(x, out_xn, xhw, xlw, fixcnt);
    k_mfma   <<<(B / 128) * 8, 256, 0, stream>>>(xhw, xlw, chw, clw, pk1, pk2, B, K);
    k_reduce2<<<B / 256, 256, 0, stream>>>(pk1, pk2, mask, train, bestidx,
                                           fixlist, fixcnt, B, K);
    k_out    <<<B / 4, 256, 0, stream>>>(out_xn, cbw, bestidx, out, B);
    k_fix    <<<256, 256, 0, stream>>>(out_xn, cbw, mask, train, fixlist, fixcnt,
                                       out, B, K);
}